// Round 1
// baseline (2301.743 us; speedup 1.0000x reference)
//
#include <hip/hip_runtime.h>
#include <hip/hip_bf16.h>

typedef __hip_bfloat16 bf16;

#define HEADS 8
#define HID 64
#define NCLS 40
#define FEAT 512

// ---------------- weight repack ----------------
// Bp[h][k][p*64+j] = W_pair[h][p*64+k][j]   (so u|v is one GEMM per head, ldb=128)
__global__ void repack_wpair(const float* __restrict__ Wp, float* __restrict__ Bp) {
    int idx = blockIdx.x * blockDim.x + threadIdx.x;
    if (idx >= 8 * 64 * 128) return;
    int h = idx >> 13;
    int rem = idx & 8191;
    int k = rem >> 7;
    int c = rem & 127;
    int p = c >> 6;
    int j = c & 63;
    Bp[idx] = Wp[h * 8192 + (p * 64 + k) * 64 + j];
}

// B2p[k][p*40+j] = W_pair_out[p*40+k][j]
__global__ void repack_wpo(const float* __restrict__ Wpo, float* __restrict__ B2p) {
    int idx = blockIdx.x * blockDim.x + threadIdx.x;
    if (idx >= 40 * 80) return;
    int k = idx / 80;
    int c = idx % 80;
    int p = c / 40;
    int j = c % 40;
    B2p[idx] = Wpo[(p * 40 + k) * 40 + j];
}

// ---------------- CSR build (group edges by src == target row) ----------------
__global__ void hist_kernel(const int* __restrict__ src, int* __restrict__ counts, int ne) {
    int i = blockIdx.x * blockDim.x + threadIdx.x;
    int stride = gridDim.x * blockDim.x;
    for (; i < ne; i += stride) atomicAdd(&counts[src[i]], 1);
}

__global__ void scan_kernel(const int* __restrict__ counts, int* __restrict__ offsets,
                            int* __restrict__ cursor, int n) {
    __shared__ int part[1024];
    int tid = threadIdx.x;
    int chunk = (n + 1023) >> 10;
    int begin = tid * chunk;
    int end = begin + chunk;
    if (end > n) end = n;
    int s = 0;
    for (int i = begin; i < end; i++) s += counts[i];
    part[tid] = s;
    __syncthreads();
    for (int d = 1; d < 1024; d <<= 1) {
        int v = 0;
        if (tid >= d) v = part[tid - d];
        __syncthreads();
        if (tid >= d) part[tid] += v;
        __syncthreads();
    }
    int run = (tid == 0) ? 0 : part[tid - 1];
    for (int i = begin; i < end; i++) {
        cursor[i] = run;
        run += counts[i];
        offsets[i + 1] = run;
    }
    if (tid == 0) offsets[0] = 0;
}

__global__ void scatter_kernel(const int* __restrict__ src, const int* __restrict__ dst,
                               int* __restrict__ cursor, int* __restrict__ dsts, int ne) {
    int i = blockIdx.x * blockDim.x + threadIdx.x;
    int stride = gridDim.x * blockDim.x;
    for (; i < ne; i += stride) {
        int pos = atomicAdd(&cursor[src[i]], 1);
        dsts[pos] = dst[i];
    }
}

// ---------------- generic tiled fp32 GEMM (64x64 tile, K-chunk 16) ----------------
__device__ __forceinline__ float ldA(const float* p) { return *p; }
__device__ __forceinline__ float ldA(const bf16* p) { return (float)*p; }
__device__ __forceinline__ void stC(float* p, float v) { *p = v; }
__device__ __forceinline__ void stC(bf16* p, float v) { *p = (bf16)v; }

template <typename AT, typename CT>
__global__ void gemm_kernel(const AT* __restrict__ A, int lda, int acol0, int acolStride,
                            const float* __restrict__ B, int ldb, long bBatchStride,
                            CT* __restrict__ C, int ldc, int ccolStride,
                            int nrows, int K, int ncols) {
    __shared__ __align__(16) float As[16][68];   // [k][m], padded
    __shared__ __align__(16) float Bs[16][64];   // [k][j]
    const int batch = blockIdx.y;
    const int colblk = blockIdx.z * 64;
    const int a0 = acol0 + batch * acolStride;
    const float* Bb = B + (size_t)batch * bBatchStride;
    const int row0 = blockIdx.x * 64;
    const int tid = threadIdx.x;           // 256 threads
    const int tm = tid >> 4, tn = tid & 15;
    float acc[4][4] = {};
    for (int k0 = 0; k0 < K; k0 += 16) {
#pragma unroll
        for (int i = 0; i < 4; i++) {
            int idx = tid + i * 256;
            int m = idx >> 4;
            int k = idx & 15;
            int gr = row0 + m;
            float v = 0.f;
            if (gr < nrows && (k0 + k) < K) v = ldA(&A[(size_t)gr * lda + a0 + k0 + k]);
            As[k][m] = v;
        }
#pragma unroll
        for (int i = 0; i < 4; i++) {
            int idx = tid + i * 256;
            int k = idx >> 6;
            int j = idx & 63;
            float v = 0.f;
            if ((k0 + k) < K && (colblk + j) < ncols) v = Bb[(size_t)(k0 + k) * ldb + colblk + j];
            Bs[k][j] = v;
        }
        __syncthreads();
#pragma unroll
        for (int k = 0; k < 16; k++) {
            float av[4], bv[4];
#pragma unroll
            for (int i = 0; i < 4; i++) av[i] = As[k][tm * 4 + i];
#pragma unroll
            for (int j = 0; j < 4; j++) bv[j] = Bs[k][tn * 4 + j];
#pragma unroll
            for (int i = 0; i < 4; i++)
#pragma unroll
                for (int j = 0; j < 4; j++) acc[i][j] += av[i] * bv[j];
        }
        __syncthreads();
    }
#pragma unroll
    for (int i = 0; i < 4; i++) {
        int gr = row0 + tm * 4 + i;
        if (gr >= nrows) continue;
#pragma unroll
        for (int j = 0; j < 4; j++) {
            int gc = colblk + tn * 4 + j;
            if (gc < ncols) stC(&C[(size_t)gr * ldc + batch * ccolStride + gc], acc[i][j]);
        }
    }
}

// ---------------- layer-1 edge/aggregation: one wave per (target, head) ----------------
// h:  bf16 [N][8*64]   cols head*64+j
// uv: bf16 [N][8*128]  u at head*128+j, v at head*128+64+j
// out x2: bf16 [N][512] = elu(elu(h_prime))
__global__ void edge_l1(const int* __restrict__ offsets, const int* __restrict__ dsts,
                        const bf16* __restrict__ h, const bf16* __restrict__ uv,
                        const float* __restrict__ a, bf16* __restrict__ x2, int n) {
    int wave = threadIdx.x >> 6;
    int lane = threadIdx.x & 63;
    int t = blockIdx.x * (blockDim.x >> 6) + wave;
    int head = blockIdx.y;
    if (t >= n) return;
    float u_t = (float)uv[(size_t)t * 1024 + head * 128 + lane];
    float a_l = a[head * 64 + lane];
    int s0 = offsets[t], s1 = offsets[t + 1];
    float acc = 0.f, rs = 0.f;
    for (int base = s0; base < s1; base += 64) {
        int cnt = s1 - base;
        if (cnt > 64) cnt = 64;
        int myd = (lane < cnt) ? dsts[base + lane] : 0;
        for (int j = 0; j < cnt; j++) {
            int d = __shfl(myd, j, 64);
            float w = u_t + (float)uv[(size_t)d * 1024 + head * 128 + 64 + lane];
            float lr = w > 0.f ? w : 0.2f * w;
            float p = a_l * lr;
#pragma unroll
            for (int m = 32; m; m >>= 1) p += __shfl_xor(p, m, 64);
            float wgt = __expf(p);
            rs += wgt;
            acc += wgt * (float)h[(size_t)d * 512 + head * 64 + lane];
        }
    }
    float hp = acc / rs;
    float e1 = hp > 0.f ? hp : expm1f(hp);
    float e2 = e1 > 0.f ? e1 : expm1f(e1);
    x2[(size_t)t * 512 + head * 64 + lane] = (bf16)e2;
}

// ---------------- layer-2 edge/aggregation ----------------
// h2: f32 [N][40], uv2: f32 [N][80] (u2 | v2), out: f32 [N][40] = elu(h_prime)
__global__ void edge_l2(const int* __restrict__ offsets, const int* __restrict__ dsts,
                        const float* __restrict__ h2, const float* __restrict__ uv2,
                        const float* __restrict__ a_out, float* __restrict__ out, int n) {
    int wave = threadIdx.x >> 6;
    int lane = threadIdx.x & 63;
    int t = blockIdx.x * (blockDim.x >> 6) + wave;
    if (t >= n) return;
    bool act = lane < 40;
    float u_t = act ? uv2[(size_t)t * 80 + lane] : 0.f;
    float a_l = act ? a_out[lane] : 0.f;
    int s0 = offsets[t], s1 = offsets[t + 1];
    float acc = 0.f, rs = 0.f;
    for (int base = s0; base < s1; base += 64) {
        int cnt = s1 - base;
        if (cnt > 64) cnt = 64;
        int myd = (lane < cnt) ? dsts[base + lane] : 0;
        for (int j = 0; j < cnt; j++) {
            int d = __shfl(myd, j, 64);
            float p = 0.f;
            float hv = 0.f;
            if (act) {
                float w = u_t + uv2[(size_t)d * 80 + 40 + lane];
                float lr = w > 0.f ? w : 0.2f * w;
                p = a_l * lr;
                hv = h2[(size_t)d * 40 + lane];
            }
#pragma unroll
            for (int m = 32; m; m >>= 1) p += __shfl_xor(p, m, 64);
            float wgt = __expf(p);
            rs += wgt;
            acc += wgt * hv;
        }
    }
    if (act) {
        float hp = acc / rs;
        out[(size_t)t * 40 + lane] = hp > 0.f ? hp : expm1f(hp);
    }
}

// ---------------- launch ----------------
extern "C" void kernel_launch(void* const* d_in, const int* in_sizes, int n_in,
                              void* d_out, int out_size, void* d_ws, size_t ws_size,
                              hipStream_t stream) {
    const float* x         = (const float*)d_in[0];
    const int*   edge      = (const int*)d_in[1];
    const float* W         = (const float*)d_in[2];
    const float* W_pair    = (const float*)d_in[3];
    const float* a         = (const float*)d_in[4];
    const float* W_out     = (const float*)d_in[5];
    const float* W_pair_out= (const float*)d_in[6];
    const float* a_out     = (const float*)d_in[7];
    float* out = (float*)d_out;

    const int n  = in_sizes[0] / FEAT;   // 50000
    const int ne = in_sizes[1] / 2;      // 1,650,000
    const int* srcArr = edge;
    const int* dstArr = edge + ne;

    char* ws = (char*)d_ws;
    size_t off = 0;
    auto alloc = [&](size_t bytes) -> void* {
        void* p = ws + off;
        off = (off + bytes + 255) & ~(size_t)255;
        return p;
    };
    bf16* h_all = (bf16*)alloc((size_t)n * 512 * sizeof(bf16));     // [N][H*64]
    bf16* uv    = (bf16*)alloc((size_t)n * 1024 * sizeof(bf16));    // [N][H*128]
    bf16* x2    = (bf16*)alloc((size_t)n * 512 * sizeof(bf16));     // [N][512]
    float* Bp   = (float*)alloc(8 * 64 * 128 * sizeof(float));
    float* B2p  = (float*)alloc(40 * 80 * sizeof(float));
    int* counts  = (int*)alloc((size_t)n * sizeof(int));
    int* offsets = (int*)alloc((size_t)(n + 1) * sizeof(int));
    int* cursor  = (int*)alloc((size_t)n * sizeof(int));
    int* dsts    = (int*)alloc((size_t)ne * sizeof(int));
    // layer-2 buffers alias h_all (dead after edge_l1)
    float* h2  = (float*)h_all;                       // [N][40] = 8 MB
    float* uv2 = (float*)((char*)h_all + (size_t)n * 40 * sizeof(float)); // [N][80] = 16 MB

    // CSR build
    hipMemsetAsync(counts, 0, (size_t)n * sizeof(int), stream);
    hist_kernel<<<2048, 256, 0, stream>>>(srcArr, counts, ne);
    scan_kernel<<<1, 1024, 0, stream>>>(counts, offsets, cursor, n);
    scatter_kernel<<<2048, 256, 0, stream>>>(srcArr, dstArr, cursor, dsts, ne);

    // weight repacks
    repack_wpair<<<(8 * 64 * 128 + 255) / 256, 256, 0, stream>>>(W_pair, Bp);
    repack_wpo<<<(40 * 80 + 255) / 256, 256, 0, stream>>>(W_pair_out, B2p);

    const int rowBlocks = (n + 63) / 64;   // 782

    // gemm1: h[n, head*64+j] = x @ W[head]
    gemm_kernel<float, bf16><<<dim3(rowBlocks, 8, 1), 256, 0, stream>>>(
        x, FEAT, 0, 0, W, 64, 512L * 64, h_all, 512, 64, n, FEAT, 64);

    // gemm_uv: uv[n, head*128 + (0..127)] = h_head @ Bp[head]  (u|v)
    gemm_kernel<bf16, bf16><<<dim3(rowBlocks, 8, 2), 256, 0, stream>>>(
        h_all, 512, 0, 64, Bp, 128, 64L * 128, uv, 1024, 128, n, 64, 128);

    // layer-1 edge phase -> x2
    edge_l1<<<dim3((n + 3) / 4, 8, 1), 256, 0, stream>>>(offsets, dsts, h_all, uv, a, x2, n);

    // gemm2: h2 = x2 @ W_out  [N,40] f32
    gemm_kernel<bf16, float><<<dim3(rowBlocks, 1, 1), 256, 0, stream>>>(
        x2, 512, 0, 0, W_out, 40, 0, h2, 40, 0, n, FEAT, 40);

    // gemm_uv2: uv2 = h2 @ B2p  [N,80] f32
    gemm_kernel<float, float><<<dim3(rowBlocks, 1, 2), 256, 0, stream>>>(
        h2, 40, 0, 0, B2p, 80, 0, uv2, 80, 0, n, 40, 80);

    // layer-2 edge phase -> out
    edge_l2<<<dim3((n + 3) / 4, 1, 1), 256, 0, stream>>>(offsets, dsts, h2, uv2, a_out, out, n);
}

// Round 2
// 1665.375 us; speedup vs baseline: 1.3821x; 1.3821x over previous
//
#include <hip/hip_runtime.h>
#include <hip/hip_bf16.h>

typedef __hip_bfloat16 bf16;

#define HEADS 8
#define HID 64
#define NCLS 40
#define FEAT 512

// ---------------- weight repack ----------------
// Bp[h][k][p*64+j] = W_pair[h][p*64+k][j]   (so u|v is one GEMM per head, ldb=128)
__global__ void repack_wpair(const float* __restrict__ Wp, float* __restrict__ Bp) {
    int idx = blockIdx.x * blockDim.x + threadIdx.x;
    if (idx >= 8 * 64 * 128) return;
    int h = idx >> 13;
    int rem = idx & 8191;
    int k = rem >> 7;
    int c = rem & 127;
    int p = c >> 6;
    int j = c & 63;
    Bp[idx] = Wp[h * 8192 + (p * 64 + k) * 64 + j];
}

// B2p[k][p*40+j] = W_pair_out[p*40+k][j]
__global__ void repack_wpo(const float* __restrict__ Wpo, float* __restrict__ B2p) {
    int idx = blockIdx.x * blockDim.x + threadIdx.x;
    if (idx >= 40 * 80) return;
    int k = idx / 80;
    int c = idx % 80;
    int p = c / 40;
    int j = c % 40;
    B2p[idx] = Wpo[(p * 40 + k) * 40 + j];
}

// ---------------- CSR build (group edges by src == target row) ----------------
__global__ void hist_kernel(const int* __restrict__ src, int* __restrict__ counts, int ne) {
    int i = blockIdx.x * blockDim.x + threadIdx.x;
    int stride = gridDim.x * blockDim.x;
    for (; i < ne; i += stride) atomicAdd(&counts[src[i]], 1);
}

__global__ void scan_kernel(const int* __restrict__ counts, int* __restrict__ offsets,
                            int* __restrict__ cursor, int n) {
    __shared__ int part[1024];
    int tid = threadIdx.x;
    int chunk = (n + 1023) >> 10;
    int begin = tid * chunk;
    int end = begin + chunk;
    if (end > n) end = n;
    int s = 0;
    for (int i = begin; i < end; i++) s += counts[i];
    part[tid] = s;
    __syncthreads();
    for (int d = 1; d < 1024; d <<= 1) {
        int v = 0;
        if (tid >= d) v = part[tid - d];
        __syncthreads();
        if (tid >= d) part[tid] += v;
        __syncthreads();
    }
    int run = (tid == 0) ? 0 : part[tid - 1];
    for (int i = begin; i < end; i++) {
        cursor[i] = run;
        run += counts[i];
        offsets[i + 1] = run;
    }
    if (tid == 0) offsets[0] = 0;
}

__global__ void scatter_kernel(const int* __restrict__ src, const int* __restrict__ dst,
                               int* __restrict__ cursor, int* __restrict__ dsts, int ne) {
    int i = blockIdx.x * blockDim.x + threadIdx.x;
    int stride = gridDim.x * blockDim.x;
    for (; i < ne; i += stride) {
        int pos = atomicAdd(&cursor[src[i]], 1);
        dsts[pos] = dst[i];
    }
}

// ---------------- generic tiled fp32 GEMM (64x64 tile, K-chunk 16) ----------------
__device__ __forceinline__ float ldA(const float* p) { return *p; }
__device__ __forceinline__ float ldA(const bf16* p) { return (float)*p; }
__device__ __forceinline__ void stC(float* p, float v) { *p = v; }
__device__ __forceinline__ void stC(bf16* p, float v) { *p = (bf16)v; }

template <typename AT, typename CT>
__global__ void gemm_kernel(const AT* __restrict__ A, int lda, int acol0, int acolStride,
                            const float* __restrict__ B, int ldb, long bBatchStride,
                            CT* __restrict__ C, int ldc, int ccolStride,
                            int nrows, int K, int ncols) {
    __shared__ __align__(16) float As[16][68];   // [k][m], padded
    __shared__ __align__(16) float Bs[16][64];   // [k][j]
    const int batch = blockIdx.y;
    const int colblk = blockIdx.z * 64;
    const int a0 = acol0 + batch * acolStride;
    const float* Bb = B + (size_t)batch * bBatchStride;
    const int row0 = blockIdx.x * 64;
    const int tid = threadIdx.x;           // 256 threads
    const int tm = tid >> 4, tn = tid & 15;
    float acc[4][4] = {};
    for (int k0 = 0; k0 < K; k0 += 16) {
#pragma unroll
        for (int i = 0; i < 4; i++) {
            int idx = tid + i * 256;
            int m = idx >> 4;
            int k = idx & 15;
            int gr = row0 + m;
            float v = 0.f;
            if (gr < nrows && (k0 + k) < K) v = ldA(&A[(size_t)gr * lda + a0 + k0 + k]);
            As[k][m] = v;
        }
#pragma unroll
        for (int i = 0; i < 4; i++) {
            int idx = tid + i * 256;
            int k = idx >> 6;
            int j = idx & 63;
            float v = 0.f;
            if ((k0 + k) < K && (colblk + j) < ncols) v = Bb[(size_t)(k0 + k) * ldb + colblk + j];
            Bs[k][j] = v;
        }
        __syncthreads();
#pragma unroll
        for (int k = 0; k < 16; k++) {
            float av[4], bv[4];
#pragma unroll
            for (int i = 0; i < 4; i++) av[i] = As[k][tm * 4 + i];
#pragma unroll
            for (int j = 0; j < 4; j++) bv[j] = Bs[k][tn * 4 + j];
#pragma unroll
            for (int i = 0; i < 4; i++)
#pragma unroll
                for (int j = 0; j < 4; j++) acc[i][j] += av[i] * bv[j];
        }
        __syncthreads();
    }
#pragma unroll
    for (int i = 0; i < 4; i++) {
        int gr = row0 + tm * 4 + i;
        if (gr >= nrows) continue;
#pragma unroll
        for (int j = 0; j < 4; j++) {
            int gc = colblk + tn * 4 + j;
            if (gc < ncols) stC(&C[(size_t)gr * ldc + batch * ccolStride + gc], acc[i][j]);
        }
    }
}

// ---------------- helpers ----------------
__device__ __forceinline__ void unpack8(const uint4 r, float o[8]) {
    o[0] = __uint_as_float(r.x << 16);
    o[1] = __uint_as_float(r.x & 0xffff0000u);
    o[2] = __uint_as_float(r.y << 16);
    o[3] = __uint_as_float(r.y & 0xffff0000u);
    o[4] = __uint_as_float(r.z << 16);
    o[5] = __uint_as_float(r.z & 0xffff0000u);
    o[6] = __uint_as_float(r.w << 16);
    o[7] = __uint_as_float(r.w & 0xffff0000u);
}

__device__ __forceinline__ void store8(float* p, const float o[8]) {
    float4 v0 = {o[0], o[1], o[2], o[3]};
    float4 v1 = {o[4], o[5], o[6], o[7]};
    *(float4*)p = v0;
    *(float4*)(p + 4) = v1;
}

__device__ __forceinline__ void store8(bf16* p, const float o[8]) {
    bf16 tmp[8];
#pragma unroll
    for (int k = 0; k < 8; k++) tmp[k] = (bf16)o[k];
    *(uint4*)p = *(const uint4*)tmp;
}

// ---------------- layer-1 edge/aggregation: one wave per target, ALL 8 heads ----------------
// lane l serves head l>>3, dims (l&7)*8 .. +7  (so h/x2 column = 8*l .. 8*l+7)
// h:  bf16 [N][512]  col head*64+dim
// uv: bf16 [N][1024] u at head*128+dim, v at head*128+64+dim
// x2: [N][512] = elu(elu(h_prime))
template <typename X2T>
__global__ void edge_l1(const int* __restrict__ offsets, const int* __restrict__ dsts,
                        const bf16* __restrict__ h, const bf16* __restrict__ uv,
                        const float* __restrict__ a, X2T* __restrict__ x2, int n) {
    const int lane = threadIdx.x & 63;
    const int wave = threadIdx.x >> 6;
    const int t = blockIdx.x * (blockDim.x >> 6) + wave;
    if (t >= n) return;
    const int head = lane >> 3;
    const int sub = lane & 7;
    const int voff = head * 128 + 64 + sub * 8;   // v chunk within uv row (elements)
    const int uoff = head * 128 + sub * 8;        // u chunk within uv row
    const int hoff = lane * 8;                    // chunk within h/x2 row

    float areg[8], ureg[8];
    {
        uint4 ur = *(const uint4*)(uv + (size_t)t * 1024 + uoff);
        unpack8(ur, ureg);
        const float4* ap = (const float4*)(a + hoff);  // a[head*64 + sub*8 + j] == a[lane*8+j]
        float4 a0 = ap[0], a1 = ap[1];
        areg[0] = a0.x; areg[1] = a0.y; areg[2] = a0.z; areg[3] = a0.w;
        areg[4] = a1.x; areg[5] = a1.y; areg[6] = a1.z; areg[7] = a1.w;
    }

    const int s0 = offsets[t], s1 = offsets[t + 1];
    float acc[8] = {0.f, 0.f, 0.f, 0.f, 0.f, 0.f, 0.f, 0.f};
    float rs = 0.f;

    for (int base = s0; base < s1; base += 64) {
        int cnt = s1 - base;
        if (cnt > 64) cnt = 64;
        int myd = (lane < cnt) ? dsts[base + lane] : 0;
        for (int j = 0; j < cnt; j++) {
            int d = __shfl(myd, j, 64);
            uint4 vr = *(const uint4*)(uv + (size_t)d * 1024 + voff);
            uint4 hr = *(const uint4*)(h + (size_t)d * 512 + hoff);
            float vv[8];
            unpack8(vr, vv);
            float p = 0.f;
#pragma unroll
            for (int k = 0; k < 8; k++) {
                float w = ureg[k] + vv[k];
                float lr = fmaxf(w, 0.2f * w);   // leaky_relu, slope 0.2 (valid since 0.2>0)
                p = fmaf(areg[k], lr, p);
            }
            // reduce over the 8 lanes of this head group
            p += __shfl_xor(p, 1, 64);
            p += __shfl_xor(p, 2, 64);
            p += __shfl_xor(p, 4, 64);
            float wgt = __expf(p);
            rs += wgt;
            float hv[8];
            unpack8(hr, hv);
#pragma unroll
            for (int k = 0; k < 8; k++) acc[k] = fmaf(wgt, hv[k], acc[k]);
        }
    }
    float inv = 1.f / rs;
    float o[8];
#pragma unroll
    for (int k = 0; k < 8; k++) {
        float hp = acc[k] * inv;
        float e1 = hp > 0.f ? hp : expm1f(hp);
        o[k] = e1 > 0.f ? e1 : expm1f(e1);
    }
    store8(x2 + (size_t)t * 512 + hoff, o);
}

// ---------------- layer-2 edge/aggregation ----------------
// h2: f32 [N][40], uv2: f32 [N][80] (u2 | v2), out: f32 [N][40] = elu(h_prime)
__global__ void edge_l2(const int* __restrict__ offsets, const int* __restrict__ dsts,
                        const float* __restrict__ h2, const float* __restrict__ uv2,
                        const float* __restrict__ a_out, float* __restrict__ out, int n) {
    int wave = threadIdx.x >> 6;
    int lane = threadIdx.x & 63;
    int t = blockIdx.x * (blockDim.x >> 6) + wave;
    if (t >= n) return;
    bool act = lane < 40;
    float u_t = act ? uv2[(size_t)t * 80 + lane] : 0.f;
    float a_l = act ? a_out[lane] : 0.f;
    int s0 = offsets[t], s1 = offsets[t + 1];
    float acc = 0.f, rs = 0.f;
    for (int base = s0; base < s1; base += 64) {
        int cnt = s1 - base;
        if (cnt > 64) cnt = 64;
        int myd = (lane < cnt) ? dsts[base + lane] : 0;
        for (int j = 0; j < cnt; j++) {
            int d = __shfl(myd, j, 64);
            float p = 0.f;
            float hv = 0.f;
            if (act) {
                float w = u_t + uv2[(size_t)d * 80 + 40 + lane];
                float lr = fmaxf(w, 0.2f * w);
                p = a_l * lr;
                hv = h2[(size_t)d * 40 + lane];
            }
#pragma unroll
            for (int m = 32; m; m >>= 1) p += __shfl_xor(p, m, 64);
            float wgt = __expf(p);
            rs += wgt;
            acc += wgt * hv;
        }
    }
    if (act) {
        float hp = acc / rs;
        out[(size_t)t * 40 + lane] = hp > 0.f ? hp : expm1f(hp);
    }
}

// ---------------- launch ----------------
extern "C" void kernel_launch(void* const* d_in, const int* in_sizes, int n_in,
                              void* d_out, int out_size, void* d_ws, size_t ws_size,
                              hipStream_t stream) {
    const float* x         = (const float*)d_in[0];
    const int*   edge      = (const int*)d_in[1];
    const float* W         = (const float*)d_in[2];
    const float* W_pair    = (const float*)d_in[3];
    const float* a         = (const float*)d_in[4];
    const float* W_out     = (const float*)d_in[5];
    const float* W_pair_out= (const float*)d_in[6];
    const float* a_out     = (const float*)d_in[7];
    float* out = (float*)d_out;

    const int n  = in_sizes[0] / FEAT;   // 50000
    const int ne = in_sizes[1] / 2;      // 1,650,000
    const int* srcArr = edge;
    const int* dstArr = edge + ne;

    // f32-x2 path needs ~264 MB of workspace; fall back to bf16 x2 otherwise.
    const size_t needF32 =
        (size_t)n * 512 * 2 +          // h
        (size_t)n * 1024 * 2 +         // uv
        (size_t)n * 512 * 4 +          // x2 f32
        (8 * 64 * 128 + 40 * 80) * 4 + // Bp, B2p
        (size_t)(3 * n + 1) * 4 +      // counts/offsets/cursor
        (size_t)ne * 4 +               // dsts
        16 * 256;                      // alignment slack
    const bool x2f32 = ws_size >= needF32;

    char* ws = (char*)d_ws;
    size_t off = 0;
    auto alloc = [&](size_t bytes) -> void* {
        void* p = ws + off;
        off = (off + bytes + 255) & ~(size_t)255;
        return p;
    };
    bf16* h_all = (bf16*)alloc((size_t)n * 512 * sizeof(bf16));     // [N][512]
    bf16* uv    = (bf16*)alloc((size_t)n * 1024 * sizeof(bf16));    // [N][1024]
    void* x2    = alloc((size_t)n * 512 * (x2f32 ? 4 : 2));         // [N][512]
    float* Bp   = (float*)alloc(8 * 64 * 128 * sizeof(float));
    float* B2p  = (float*)alloc(40 * 80 * sizeof(float));
    int* counts  = (int*)alloc((size_t)n * sizeof(int));
    int* offsets = (int*)alloc((size_t)(n + 1) * sizeof(int));
    int* cursor  = (int*)alloc((size_t)n * sizeof(int));
    int* dsts    = (int*)alloc((size_t)ne * sizeof(int));
    // layer-2 buffers alias h_all (dead after edge_l1)
    float* h2  = (float*)h_all;                       // [N][40] = 8 MB
    float* uv2 = (float*)((char*)h_all + (size_t)n * 40 * sizeof(float)); // [N][80] = 16 MB

    // CSR build
    hipMemsetAsync(counts, 0, (size_t)n * sizeof(int), stream);
    hist_kernel<<<2048, 256, 0, stream>>>(srcArr, counts, ne);
    scan_kernel<<<1, 1024, 0, stream>>>(counts, offsets, cursor, n);
    scatter_kernel<<<2048, 256, 0, stream>>>(srcArr, dstArr, cursor, dsts, ne);

    // weight repacks
    repack_wpair<<<(8 * 64 * 128 + 255) / 256, 256, 0, stream>>>(W_pair, Bp);
    repack_wpo<<<(40 * 80 + 255) / 256, 256, 0, stream>>>(W_pair_out, B2p);

    const int rowBlocks = (n + 63) / 64;   // 782

    // gemm1: h[n, head*64+j] = x @ W[head]
    gemm_kernel<float, bf16><<<dim3(rowBlocks, 8, 1), 256, 0, stream>>>(
        x, FEAT, 0, 0, W, 64, 512L * 64, h_all, 512, 64, n, FEAT, 64);

    // gemm_uv: uv[n, head*128 + (0..127)] = h_head @ Bp[head]  (u|v)
    gemm_kernel<bf16, bf16><<<dim3(rowBlocks, 8, 2), 256, 0, stream>>>(
        h_all, 512, 0, 64, Bp, 128, 64L * 128, uv, 1024, 128, n, 64, 128);

    // layer-1 edge phase -> x2 (one wave per target, all heads)
    if (x2f32) {
        edge_l1<float><<<dim3((n + 3) / 4), 256, 0, stream>>>(
            offsets, dsts, h_all, uv, a, (float*)x2, n);
        gemm_kernel<float, float><<<dim3(rowBlocks, 1, 1), 256, 0, stream>>>(
            (const float*)x2, 512, 0, 0, W_out, 40, 0, h2, 40, 0, n, FEAT, 40);
    } else {
        edge_l1<bf16><<<dim3((n + 3) / 4), 256, 0, stream>>>(
            offsets, dsts, h_all, uv, a, (bf16*)x2, n);
        gemm_kernel<bf16, float><<<dim3(rowBlocks, 1, 1), 256, 0, stream>>>(
            (const bf16*)x2, 512, 0, 0, W_out, 40, 0, h2, 40, 0, n, FEAT, 40);
    }

    // gemm_uv2: uv2 = h2 @ B2p  [N,80] f32
    gemm_kernel<float, float><<<dim3(rowBlocks, 1, 2), 256, 0, stream>>>(
        h2, 40, 0, 0, B2p, 80, 0, uv2, 80, 0, n, 40, 80);

    // layer-2 edge phase -> out
    edge_l2<<<dim3((n + 3) / 4), 256, 0, stream>>>(offsets, dsts, h2, uv2, a_out, out, n);
}

// Round 3
// 1122.636 us; speedup vs baseline: 2.0503x; 1.4835x over previous
//
#include <hip/hip_runtime.h>
#include <hip/hip_bf16.h>
#include <hip/hip_fp16.h>

typedef _Float16 f16;
typedef _Float16 f16x8 __attribute__((ext_vector_type(8)));
typedef float f32x4 __attribute__((ext_vector_type(4)));

#define HEADS 8
#define HID 64
#define NCLS 40
#define FEAT 512

// ---------------- packing / conversion ----------------
__global__ void conv_x(const float* __restrict__ x, f16* __restrict__ xh, int total4) {
    int i = blockIdx.x * blockDim.x + threadIdx.x;
    int stride = gridDim.x * blockDim.x;
    for (; i < total4; i += stride) {
        float4 v = ((const float4*)x)[i];
        f16 o[4] = {(f16)v.x, (f16)v.y, (f16)v.z, (f16)v.w};
        *(ulong1*)(xh + i * 4) = *(ulong1*)o;
    }
}

// Wh_t[c][k] = W[c>>6][k][c&63], c in [0,512)   ([col][K] f16)
__global__ void pack_Wh(const float* __restrict__ W, f16* __restrict__ Wt) {
    int idx = blockIdx.x * blockDim.x + threadIdx.x;
    if (idx >= 512 * 512) return;
    int c = idx >> 9, k = idx & 511;
    Wt[idx] = (f16)W[(c >> 6) * 512 * 64 + k * 64 + (c & 63)];
}

// Bp_t[head][c][k] = W_pair[head][(c>>6)*64 + k][c&63], c in [0,128), k in [0,64)
__global__ void pack_Bp(const float* __restrict__ Wp, f16* __restrict__ Bt) {
    int idx = blockIdx.x * blockDim.x + threadIdx.x;
    if (idx >= 8 * 128 * 64) return;
    int head = idx >> 13, c = (idx >> 6) & 127, k = idx & 63;
    Bt[idx] = (f16)Wp[head * 8192 + ((c >> 6) * 64 + k) * 64 + (c & 63)];
}

// Wo_t[c][k] = W_out[k][c], c in [0,40)
__global__ void pack_Wo(const float* __restrict__ Wo, f16* __restrict__ Wt) {
    int idx = blockIdx.x * blockDim.x + threadIdx.x;
    if (idx >= 40 * 512) return;
    int c = idx >> 9, k = idx & 511;
    Wt[idx] = (f16)Wo[k * 40 + c];
}

// B2p[k][p*40+j] = W_pair_out[p*40+k][j]  (f32, for the tiny vector GEMM)
__global__ void repack_wpo(const float* __restrict__ Wpo, float* __restrict__ B2p) {
    int idx = blockIdx.x * blockDim.x + threadIdx.x;
    if (idx >= 40 * 80) return;
    int k = idx / 80;
    int c = idx % 80;
    int p = c / 40;
    int j = c % 40;
    B2p[idx] = Wpo[(p * 40 + k) * 40 + j];
}

// ---------------- CSR build (group edges by src == target row) ----------------
__global__ void hist_kernel(const int* __restrict__ src, int* __restrict__ counts, int ne) {
    int i = blockIdx.x * blockDim.x + threadIdx.x;
    int stride = gridDim.x * blockDim.x;
    for (; i < ne; i += stride) atomicAdd(&counts[src[i]], 1);
}

__global__ void scan_kernel(const int* __restrict__ counts, int* __restrict__ offsets,
                            int* __restrict__ cursor, int n) {
    __shared__ int part[1024];
    int tid = threadIdx.x;
    int chunk = (n + 1023) >> 10;
    int begin = tid * chunk;
    int end = begin + chunk;
    if (end > n) end = n;
    int s = 0;
    for (int i = begin; i < end; i++) s += counts[i];
    part[tid] = s;
    __syncthreads();
    for (int d = 1; d < 1024; d <<= 1) {
        int v = 0;
        if (tid >= d) v = part[tid - d];
        __syncthreads();
        if (tid >= d) part[tid] += v;
        __syncthreads();
    }
    int run = (tid == 0) ? 0 : part[tid - 1];
    for (int i = begin; i < end; i++) {
        cursor[i] = run;
        run += counts[i];
        offsets[i + 1] = run;
    }
    if (tid == 0) offsets[0] = 0;
}

__global__ void scatter_kernel(const int* __restrict__ src, const int* __restrict__ dst,
                               int* __restrict__ cursor, int* __restrict__ dsts, int ne) {
    int i = blockIdx.x * blockDim.x + threadIdx.x;
    int stride = gridDim.x * blockDim.x;
    for (; i < ne; i += stride) {
        int pos = atomicAdd(&cursor[src[i]], 1);
        dsts[pos] = dst[i];
    }
}

// ---------------- MFMA f16 GEMM: 128x128 tile, BK=32, 4 waves ----------------
__device__ __forceinline__ void stC(float* p, float v) { *p = v; }
__device__ __forceinline__ void stC(f16* p, float v) { *p = (f16)v; }

// A [M][lda] f16 (cols a0.. a0+K), Bt [batch][ncols][K] f16 (transposed), C [M][ldc]
template <typename CT>
__global__ __launch_bounds__(256)
void gemm_mfma(const f16* __restrict__ A, int lda, int acol0, int acolStride,
               const f16* __restrict__ Bt, long bBatchStride, int K,
               CT* __restrict__ C, int ldc, int ccolStride,
               int nrows, int ncols) {
    __shared__ f16 As[128][40];   // BK=32 padded to 40 (80B rows -> 2-way max on b128 reads)
    __shared__ f16 Bs[128][40];
    const int batch = blockIdx.y;
    const int row0 = blockIdx.x * 128;
    const int col0 = blockIdx.z * 128;
    const int a0 = acol0 + batch * acolStride;
    const f16* Bb = Bt + (size_t)batch * bBatchStride;
    const int tid = threadIdx.x;
    const int lane = tid & 63;
    const int wave = tid >> 6;
    const int wr = (wave >> 1) * 64;
    const int wc = (wave & 1) * 64;
    f32x4 acc[4][4] = {};

    for (int k0 = 0; k0 < K; k0 += 32) {
#pragma unroll
        for (int i = 0; i < 2; i++) {
            int idx = tid + i * 256;
            int r = idx >> 2, ch = idx & 3;
            int gr = row0 + r;
            f16x8 val = {};
            if (gr < nrows) val = *(const f16x8*)(A + (size_t)gr * lda + a0 + k0 + ch * 8);
            *(f16x8*)(&As[r][ch * 8]) = val;
        }
#pragma unroll
        for (int i = 0; i < 2; i++) {
            int idx = tid + i * 256;
            int r = idx >> 2, ch = idx & 3;
            int gc = col0 + r;
            f16x8 val = {};
            if (gc < ncols) val = *(const f16x8*)(Bb + (size_t)gc * K + k0 + ch * 8);
            *(f16x8*)(&Bs[r][ch * 8]) = val;
        }
        __syncthreads();
        f16x8 af[4], bf[4];
#pragma unroll
        for (int t = 0; t < 4; t++)
            af[t] = *(const f16x8*)(&As[wr + t * 16 + (lane & 15)][(lane >> 4) * 8]);
#pragma unroll
        for (int t = 0; t < 4; t++)
            bf[t] = *(const f16x8*)(&Bs[wc + t * 16 + (lane & 15)][(lane >> 4) * 8]);
#pragma unroll
        for (int i = 0; i < 4; i++)
#pragma unroll
            for (int j = 0; j < 4; j++)
                acc[i][j] = __builtin_amdgcn_mfma_f32_16x16x32_f16(af[i], bf[j], acc[i][j], 0, 0, 0);
        __syncthreads();
    }
    // C/D layout: col = lane&15, row = (lane>>4)*4 + r   [HW-verified]
    const int crow = (lane >> 4) * 4;
    const int ccol = lane & 15;
#pragma unroll
    for (int i = 0; i < 4; i++) {
#pragma unroll
        for (int j = 0; j < 4; j++) {
            int gc = col0 + wc + j * 16 + ccol;
            if (gc >= ncols) continue;
#pragma unroll
            for (int r = 0; r < 4; r++) {
                int gr = row0 + wr + i * 16 + crow + r;
                if (gr < nrows)
                    stC(&C[(size_t)gr * ldc + (size_t)batch * ccolStride + gc], acc[i][j][r]);
            }
        }
    }
}

// ---------------- tiny fp32 vector GEMM (kept for uv2: K=40, N=80) ----------------
__global__ void gemm_kernel(const float* __restrict__ A, int lda,
                            const float* __restrict__ B, int ldb,
                            float* __restrict__ C, int ldc,
                            int nrows, int K, int ncols) {
    __shared__ __align__(16) float As[16][68];
    __shared__ __align__(16) float Bs[16][64];
    const int colblk = blockIdx.z * 64;
    const int row0 = blockIdx.x * 64;
    const int tid = threadIdx.x;
    const int tm = tid >> 4, tn = tid & 15;
    float acc[4][4] = {};
    for (int k0 = 0; k0 < K; k0 += 16) {
#pragma unroll
        for (int i = 0; i < 4; i++) {
            int idx = tid + i * 256;
            int m = idx >> 4;
            int k = idx & 15;
            int gr = row0 + m;
            float v = 0.f;
            if (gr < nrows && (k0 + k) < K) v = A[(size_t)gr * lda + k0 + k];
            As[k][m] = v;
        }
#pragma unroll
        for (int i = 0; i < 4; i++) {
            int idx = tid + i * 256;
            int k = idx >> 6;
            int j = idx & 63;
            float v = 0.f;
            if ((k0 + k) < K && (colblk + j) < ncols) v = B[(size_t)(k0 + k) * ldb + colblk + j];
            Bs[k][j] = v;
        }
        __syncthreads();
#pragma unroll
        for (int k = 0; k < 16; k++) {
            float av[4], bv[4];
#pragma unroll
            for (int i = 0; i < 4; i++) av[i] = As[k][tm * 4 + i];
#pragma unroll
            for (int j = 0; j < 4; j++) bv[j] = Bs[k][tn * 4 + j];
#pragma unroll
            for (int i = 0; i < 4; i++)
#pragma unroll
                for (int j = 0; j < 4; j++) acc[i][j] += av[i] * bv[j];
        }
        __syncthreads();
    }
#pragma unroll
    for (int i = 0; i < 4; i++) {
        int gr = row0 + tm * 4 + i;
        if (gr >= nrows) continue;
#pragma unroll
        for (int j = 0; j < 4; j++) {
            int gc = colblk + tn * 4 + j;
            if (gc < ncols) C[(size_t)gr * ldc + gc] = acc[i][j];
        }
    }
}

// ---------------- helpers ----------------
__device__ __forceinline__ void unpack8h(const uint4 r, float o[8]) {
    const f16* p = (const f16*)&r;
#pragma unroll
    for (int k = 0; k < 8; k++) o[k] = (float)p[k];
}

__device__ __forceinline__ void store8h(f16* p, const float o[8]) {
    f16x8 v;
#pragma unroll
    for (int k = 0; k < 8; k++) v[k] = (f16)o[k];
    *(f16x8*)p = v;
}

// ---------------- layer-1 edge/aggregation: one wave per target, ALL 8 heads ----------------
// lane l serves head l>>3, dims (l&7)*8 .. +7
// h:  f16 [N][512], uv: f16 [N][1024] (u at head*128+d, v at head*128+64+d), x2: f16 [N][512]
__global__ void edge_l1(const int* __restrict__ offsets, const int* __restrict__ dsts,
                        const f16* __restrict__ h, const f16* __restrict__ uv,
                        const float* __restrict__ a, f16* __restrict__ x2, int n) {
    const int lane = threadIdx.x & 63;
    const int wave = threadIdx.x >> 6;
    const int t = blockIdx.x * (blockDim.x >> 6) + wave;
    if (t >= n) return;
    const int head = lane >> 3;
    const int sub = lane & 7;
    const int voff = head * 128 + 64 + sub * 8;
    const int uoff = head * 128 + sub * 8;
    const int hoff = lane * 8;

    float areg[8], ureg[8];
    {
        uint4 ur = *(const uint4*)(uv + (size_t)t * 1024 + uoff);
        unpack8h(ur, ureg);
        const float4* ap = (const float4*)(a + hoff);
        float4 a0 = ap[0], a1 = ap[1];
        areg[0] = a0.x; areg[1] = a0.y; areg[2] = a0.z; areg[3] = a0.w;
        areg[4] = a1.x; areg[5] = a1.y; areg[6] = a1.z; areg[7] = a1.w;
    }

    const int s0 = offsets[t], s1 = offsets[t + 1];
    float acc[8] = {0.f, 0.f, 0.f, 0.f, 0.f, 0.f, 0.f, 0.f};
    float rs = 0.f;

    for (int base = s0; base < s1; base += 64) {
        int cnt = s1 - base;
        if (cnt > 64) cnt = 64;
        int myd = (lane < cnt) ? dsts[base + lane] : 0;
        for (int j = 0; j < cnt; j++) {
            int d = __shfl(myd, j, 64);
            uint4 vr = *(const uint4*)(uv + (size_t)d * 1024 + voff);
            uint4 hr = *(const uint4*)(h + (size_t)d * 512 + hoff);
            float vv[8];
            unpack8h(vr, vv);
            float p = 0.f;
#pragma unroll
            for (int k = 0; k < 8; k++) {
                float w = ureg[k] + vv[k];
                float lr = fmaxf(w, 0.2f * w);
                p = fmaf(areg[k], lr, p);
            }
            p += __shfl_xor(p, 1, 64);
            p += __shfl_xor(p, 2, 64);
            p += __shfl_xor(p, 4, 64);
            float wgt = __expf(p);
            rs += wgt;
            float hv[8];
            unpack8h(hr, hv);
#pragma unroll
            for (int k = 0; k < 8; k++) acc[k] = fmaf(wgt, hv[k], acc[k]);
        }
    }
    float inv = 1.f / rs;
    float o[8];
#pragma unroll
    for (int k = 0; k < 8; k++) {
        float hp = acc[k] * inv;
        float e1 = hp > 0.f ? hp : expm1f(hp);
        o[k] = e1 > 0.f ? e1 : expm1f(e1);
    }
    store8h(x2 + (size_t)t * 512 + hoff, o);
}

// ---------------- layer-2 edge/aggregation ----------------
__global__ void edge_l2(const int* __restrict__ offsets, const int* __restrict__ dsts,
                        const float* __restrict__ h2, const float* __restrict__ uv2,
                        const float* __restrict__ a_out, float* __restrict__ out, int n) {
    int wave = threadIdx.x >> 6;
    int lane = threadIdx.x & 63;
    int t = blockIdx.x * (blockDim.x >> 6) + wave;
    if (t >= n) return;
    bool act = lane < 40;
    float u_t = act ? uv2[(size_t)t * 80 + lane] : 0.f;
    float a_l = act ? a_out[lane] : 0.f;
    int s0 = offsets[t], s1 = offsets[t + 1];
    float acc = 0.f, rs = 0.f;
    for (int base = s0; base < s1; base += 64) {
        int cnt = s1 - base;
        if (cnt > 64) cnt = 64;
        int myd = (lane < cnt) ? dsts[base + lane] : 0;
        for (int j = 0; j < cnt; j++) {
            int d = __shfl(myd, j, 64);
            float p = 0.f;
            float hv = 0.f;
            if (act) {
                float w = u_t + uv2[(size_t)d * 80 + 40 + lane];
                float lr = fmaxf(w, 0.2f * w);
                p = a_l * lr;
                hv = h2[(size_t)d * 40 + lane];
            }
#pragma unroll
            for (int m = 32; m; m >>= 1) p += __shfl_xor(p, m, 64);
            float wgt = __expf(p);
            rs += wgt;
            acc += wgt * hv;
        }
    }
    if (act) {
        float hp = acc / rs;
        out[(size_t)t * 40 + lane] = hp > 0.f ? hp : expm1f(hp);
    }
}

// ---------------- launch ----------------
extern "C" void kernel_launch(void* const* d_in, const int* in_sizes, int n_in,
                              void* d_out, int out_size, void* d_ws, size_t ws_size,
                              hipStream_t stream) {
    const float* x         = (const float*)d_in[0];
    const int*   edge      = (const int*)d_in[1];
    const float* W         = (const float*)d_in[2];
    const float* W_pair    = (const float*)d_in[3];
    const float* a         = (const float*)d_in[4];
    const float* W_out     = (const float*)d_in[5];
    const float* W_pair_out= (const float*)d_in[6];
    const float* a_out     = (const float*)d_in[7];
    float* out = (float*)d_out;

    const int n  = in_sizes[0] / FEAT;   // 50000
    const int ne = in_sizes[1] / 2;      // 1,650,000
    const int* srcArr = edge;
    const int* dstArr = edge + ne;

    char* ws = (char*)d_ws;
    size_t off = 0;
    auto alloc = [&](size_t bytes) -> void* {
        void* p = ws + off;
        off = (off + bytes + 255) & ~(size_t)255;
        return p;
    };
    f16* x_h  = (f16*)alloc((size_t)n * 512 * sizeof(f16));      // [N][512]; later aliased by x2
    f16* h    = (f16*)alloc((size_t)n * 512 * sizeof(f16));      // [N][512]; later aliased by h2/uv2
    f16* uv   = (f16*)alloc((size_t)n * 1024 * sizeof(f16));     // [N][1024]
    f16* Wh_t = (f16*)alloc(512 * 512 * sizeof(f16));
    f16* Bp_t = (f16*)alloc(8 * 128 * 64 * sizeof(f16));
    f16* Wo_t = (f16*)alloc(40 * 512 * sizeof(f16));
    float* B2p = (float*)alloc(40 * 80 * sizeof(float));
    int* counts  = (int*)alloc((size_t)n * sizeof(int));
    int* offsets = (int*)alloc((size_t)(n + 1) * sizeof(int));
    int* cursor  = (int*)alloc((size_t)n * sizeof(int));
    int* dsts    = (int*)alloc((size_t)ne * sizeof(int));
    f16* x2 = x_h;                                   // x_h dead after gemm_h
    float* h2  = (float*)h;                          // h dead after edge_l1
    float* uv2 = (float*)((char*)h + (size_t)n * 40 * sizeof(float));

    // CSR build
    hipMemsetAsync(counts, 0, (size_t)n * sizeof(int), stream);
    hist_kernel<<<2048, 256, 0, stream>>>(srcArr, counts, ne);
    scan_kernel<<<1, 1024, 0, stream>>>(counts, offsets, cursor, n);
    scatter_kernel<<<2048, 256, 0, stream>>>(srcArr, dstArr, cursor, dsts, ne);

    // conversions / packs
    conv_x<<<2048, 256, 0, stream>>>(x, x_h, n * 512 / 4);
    pack_Wh<<<(512 * 512 + 255) / 256, 256, 0, stream>>>(W, Wh_t);
    pack_Bp<<<(8 * 128 * 64 + 255) / 256, 256, 0, stream>>>(W_pair, Bp_t);
    pack_Wo<<<(40 * 512 + 255) / 256, 256, 0, stream>>>(W_out, Wo_t);
    repack_wpo<<<(40 * 80 + 255) / 256, 256, 0, stream>>>(W_pair_out, B2p);

    const int mBlocks = (n + 127) / 128;   // 391

    // h = x_h @ Wh   [N,512] f16   (grid z = 4 col-blocks)
    gemm_mfma<f16><<<dim3(mBlocks, 1, 4), 256, 0, stream>>>(
        x_h, 512, 0, 0, Wh_t, 0, 512, h, 512, 0, n, 512);

    // uv[:, head*128+c] = h[:, head*64 + k] @ Bp_t[head]   (K=64, per-head batch)
    gemm_mfma<f16><<<dim3(mBlocks, 8, 1), 256, 0, stream>>>(
        h, 512, 0, 64, Bp_t, 128L * 64, 64, uv, 1024, 128, n, 128);

    // layer-1 edge phase -> x2 (aliases x_h)
    edge_l1<<<dim3((n + 3) / 4), 256, 0, stream>>>(offsets, dsts, h, uv, a, x2, n);

    // h2 = x2 @ W_out  [N,40] f32 (aliases h)
    gemm_mfma<float><<<dim3(mBlocks, 1, 1), 256, 0, stream>>>(
        x2, 512, 0, 0, Wo_t, 0, 512, h2, 40, 0, n, 40);

    // uv2 = h2 @ B2p  [N,80] f32
    gemm_kernel<<<dim3((n + 63) / 64, 1, 2), 256, 0, stream>>>(
        h2, 40, B2p, 80, uv2, 80, n, 40, 80);

    // layer-2 edge phase -> out
    edge_l2<<<dim3((n + 3) / 4), 256, 0, stream>>>(offsets, dsts, h2, uv2, a_out, out, n);
}